// Round 15
// baseline (1597.901 us; speedup 1.0000x reference)
//
#include <hip/hip_runtime.h>
#include <hip/hip_bf16.h>
#include <math.h>

// ---------------------------------------------------------------------------
// GAT: 2x GATConv(heads=1) + global mean pool + FC(64->2)
// R15: src-tiled LDS-accumulator aggregate. The old gather-aggregate was
//      pinned at 58us/172MB (5 measurements): 8 per-XCD L2s each caching
//      random rows of the 12.8MB h16 (hit 26%). New: one block per 128-dst
//      half-bucket, fp32 accumulators in LDS, edges counting-sorted by
//      src>>14 (8 tiles x 2MiB); all 782 blocks resident (4/CU, 39.5KB LDS)
//      process tiles in the same order -> per-XCD L2 holds current tile.
//      Consumes pairs directly: build_csr/rowptr/srcs DELETED (7 dispatches).
// Partition (R13), GEMM (R14), pool_fc (R11) unchanged.
// ---------------------------------------------------------------------------

#define NPB 256          // nodes per parent bucket (partition granularity)
#define EPB 4096         // edges per partition block (256 thr x 16)
#define PSTRIDE 4608     // slots per parent bucket (lambda=4092, +8 sigma)
#define XPAD 68          // gemm xs pad
#define TSHIFT 14        // src tile = src>>14 (8 tiles x 16384 nodes = 2MiB h16)
#define NTILE 8
#define SIDX_CAP 2560    // per-half-bucket edge cap (lambda=2046, +11 sigma)

__device__ __forceinline__ unsigned int f2bf(float v) {
    unsigned int b = __float_as_uint(v);
    b += 0x7FFFu + ((b >> 16) & 1u);   // round-to-nearest-even
    return b >> 16;
}

// --- init: zero bucket cursors ----------------------------------------------
__global__ __launch_bounds__(256) void init_all(int* __restrict__ bcur, int NB) {
    int i = blockIdx.x * 256 + threadIdx.x;
    if (i < NB) bcur[i] = 0;
}

// --- partition edges into fixed-stride dst-buckets (packed uint32) ----------
__global__ __launch_bounds__(256) void partition(const int* __restrict__ ei,
                                                 int E, int NB,
                                                 int* __restrict__ bcur,
                                                 unsigned int* __restrict__ pairs) {
    __shared__ int h[512];
    __shared__ int hb[512];
    int t = threadIdx.x;
    for (int i = t; i < 512; i += 256) h[i] = 0;
    __syncthreads();
    int i0 = blockIdx.x * EPB;
    unsigned int val[16];
    int bk[16], r[16];
#pragma unroll
    for (int k = 0; k < 16; k++) {
        int i = i0 + k * 256 + t;
        bk[k] = -1;
        if (i < E) {
            int s = ei[i];
            int d = ei[E + i];
            bk[k] = d >> 8;
            val[k] = (unsigned)s | ((unsigned)(d & 255) << 24);
            r[k] = atomicAdd(&h[bk[k]], 1);
        }
    }
    __syncthreads();
    for (int b = t; b < NB; b += 256)
        hb[b] = h[b] ? atomicAdd(&bcur[b], h[b]) : 0;
    __syncthreads();
#pragma unroll
    for (int k = 0; k < 16; k++) {
        if (bk[k] < 0) continue;
        int pos = hb[bk[k]] + r[k];
        if (pos < PSTRIDE)                 // overflow guard (stat. impossible)
            pairs[(size_t)bk[k] * PSTRIDE + pos] = val[k];
    }
}

// --- tiled node GEMM: 64 nodes x 64 cols per block, 4x4 per thread ----------
template <int IN_DIM>
__global__ __launch_bounds__(256) void node_gemm(const float* __restrict__ x,
                                                 const float* __restrict__ W,
                                                 const float* __restrict__ a_src,
                                                 const float* __restrict__ a_dst,
                                                 const float* __restrict__ bias_in,
                                                 float slope_in,
                                                 unsigned short* __restrict__ h16,
                                                 float* __restrict__ al_s,
                                                 float* __restrict__ al_d,
                                                 int n) {
    __shared__ float Ws[IN_DIM * 64];
    __shared__ float xs[IN_DIM][XPAD];
    int t = threadIdx.x;
    int nbase = blockIdx.x * 64;

    for (int idx = t; idx < IN_DIM * 16; idx += 256)
        ((float4*)Ws)[idx] = ((const float4*)W)[idx];
    const float* xb = x + (size_t)nbase * IN_DIM;
    int lim = min(64, n - nbase) * IN_DIM;
    for (int idx = t; idx < 64 * IN_DIM; idx += 256) {
        int node = idx / IN_DIM;
        int k = idx - node * IN_DIM;
        float v = 0.0f;
        if (idx < lim) {
            v = xb[idx];                       // contiguous, fully coalesced
            if (bias_in) {
                v += bias_in[k];
                v = (v >= 0.0f) ? v : slope_in * v;
            }
        }
        xs[k][node] = v;
    }
    __syncthreads();

    int cg = t & 15;    // col group: cols 4cg..4cg+3
    int ng = t >> 4;    // node group: nodes 4ng..4ng+3
    float acc[4][4] = {};
#pragma unroll 8
    for (int k = 0; k < IN_DIM; k++) {
        float4 xv = *(const float4*)&xs[k][ng * 4];
        float4 wv = *(const float4*)&Ws[k * 64 + cg * 4];
        float xa[4] = {xv.x, xv.y, xv.z, xv.w};
        float wa[4] = {wv.x, wv.y, wv.z, wv.w};
#pragma unroll
        for (int i = 0; i < 4; i++)
#pragma unroll
            for (int j = 0; j < 4; j++)
                acc[i][j] += xa[i] * wa[j];
    }

    float4 as4 = *(const float4*)(a_src + cg * 4);
    float4 ad4 = *(const float4*)(a_dst + cg * 4);
#pragma unroll
    for (int i = 0; i < 4; i++) {
        int node = nbase + ng * 4 + i;
        if (node < n) {
            uint2 p;
            p.x = f2bf(acc[i][0]) | (f2bf(acc[i][1]) << 16);
            p.y = f2bf(acc[i][2]) | (f2bf(acc[i][3]) << 16);
            *(uint2*)(h16 + (size_t)node * 64 + cg * 4) = p;
        }
        float vs = acc[i][0] * as4.x + acc[i][1] * as4.y +
                   acc[i][2] * as4.z + acc[i][3] * as4.w;
        float vd = acc[i][0] * ad4.x + acc[i][1] * ad4.y +
                   acc[i][2] * ad4.z + acc[i][3] * ad4.w;
#pragma unroll
        for (int o = 8; o; o >>= 1) {
            vs += __shfl_xor(vs, o);
            vd += __shfl_xor(vd, o);
        }
        if (cg == 0 && node < n) { al_s[node] = vs; al_d[node] = vd; }
    }
}

// --- src-tiled LDS-accumulator aggregate ------------------------------------
// Block = 128-dst half-bucket. acc[dl][feat] fp32 in LDS (stride 65 -> 2-way
// banks per 8-lane group). Edges sorted by src-tile; all blocks walk tiles in
// the same order (all resident) so per-XCD L2 holds the current 2MiB tile.
__device__ __forceinline__ void lds_atom8(float* row, uint4 q, float w) {
    atomicAdd(&row[0], w * __uint_as_float(q.x << 16));
    atomicAdd(&row[1], w * __uint_as_float(q.x & 0xFFFF0000u));
    atomicAdd(&row[2], w * __uint_as_float(q.y << 16));
    atomicAdd(&row[3], w * __uint_as_float(q.y & 0xFFFF0000u));
    atomicAdd(&row[4], w * __uint_as_float(q.z << 16));
    atomicAdd(&row[5], w * __uint_as_float(q.z & 0xFFFF0000u));
    atomicAdd(&row[6], w * __uint_as_float(q.w << 16));
    atomicAdd(&row[7], w * __uint_as_float(q.w & 0xFFFF0000u));
}

__global__ __launch_bounds__(256) void gat_aggregate(
        const unsigned int* __restrict__ pairs,
        const int* __restrict__ bcur,
        const float* __restrict__ als,
        const float* __restrict__ ald,
        const unsigned short* __restrict__ h16,
        float* __restrict__ hout, int n) {
    __shared__ float acc[128][65];
    __shared__ float smv[128];
    __shared__ float alds[128];
    __shared__ unsigned short sidx[SIDX_CAP];
    __shared__ int bins[NTILE];
    __shared__ int mctr;

    int blk = blockIdx.x;
    int pbk = blk >> 1, half = blk & 1;
    int d0 = (pbk << 8) + (half << 7);
    int nbk = min(128, n - d0);
    if (nbk <= 0) return;
    int t = threadIdx.x;
    int cnt = min(bcur[pbk], PSTRIDE);
    const unsigned int* pb = pairs + (size_t)pbk * PSTRIDE;

    if (t < 128) alds[t] = (t < nbk) ? ald[d0 + t] : 0.0f;
    if (t < NTILE) bins[t] = 0;
    __syncthreads();

    int grp = t >> 3, lane = t & 7;

    // self-loop init (exclusive rows -> plain stores) + tile histogram
    for (int r = grp; r < 128; r += 32) {
        if (r < nbk) {
            int d = d0 + r;
            float e = als[d] + alds[r];
            e = (e >= 0.0f) ? e : 0.2f * e;
            float w = __expf(e);
            uint4 q = *(const uint4*)(h16 + (size_t)d * 64 + lane * 8);
            float* row = &acc[r][lane * 8];
            row[0] = w * __uint_as_float(q.x << 16);
            row[1] = w * __uint_as_float(q.x & 0xFFFF0000u);
            row[2] = w * __uint_as_float(q.y << 16);
            row[3] = w * __uint_as_float(q.y & 0xFFFF0000u);
            row[4] = w * __uint_as_float(q.z << 16);
            row[5] = w * __uint_as_float(q.z & 0xFFFF0000u);
            row[6] = w * __uint_as_float(q.w << 16);
            row[7] = w * __uint_as_float(q.w & 0xFFFF0000u);
            if (lane == 0) smv[r] = w;
        }
    }
    for (int j = t; j < cnt; j += 256) {
        unsigned p = pb[j];
        if ((int)(p >> 31) == half || ((p >> 31) == 0 && half == 0)) {}
        int dlow = (int)(p >> 24);
        if ((dlow >> 7) == half)
            atomicAdd(&bins[(p & 0x00FFFFFFu) >> TSHIFT], 1);
    }
    __syncthreads();
    if (t == 0) {
        int a = 0;
        for (int i = 0; i < NTILE; i++) { int v = bins[i]; bins[i] = a; a += v; }
        mctr = min(a, SIDX_CAP);
    }
    __syncthreads();
    for (int j = t; j < cnt; j += 256) {
        unsigned p = pb[j];
        int dlow = (int)(p >> 24);
        if ((dlow >> 7) == half) {
            int pos = atomicAdd(&bins[(p & 0x00FFFFFFu) >> TSHIFT], 1);
            if (pos < SIDX_CAP) sidx[pos] = (unsigned short)j;
        }
    }
    __syncthreads();
    int m = mctr;

    // edge loop over tile-sorted index, 8 lanes/edge, 2x unroll
    int i = grp;
    for (; i + 32 < m; i += 64) {
        int j0 = sidx[i], j1 = sidx[i + 32];
        unsigned p0 = pb[j0], p1 = pb[j1];
        int s0 = (int)(p0 & 0x00FFFFFFu), s1 = (int)(p1 & 0x00FFFFFFu);
        int dl0 = (int)(p0 >> 24) & 127, dl1 = (int)(p1 >> 24) & 127;
        uint4 q0 = *(const uint4*)(h16 + (size_t)s0 * 64 + lane * 8);
        uint4 q1 = *(const uint4*)(h16 + (size_t)s1 * 64 + lane * 8);
        float e0 = als[s0] + alds[dl0];
        float e1 = als[s1] + alds[dl1];
        e0 = (e0 >= 0.0f) ? e0 : 0.2f * e0;
        e1 = (e1 >= 0.0f) ? e1 : 0.2f * e1;
        float w0 = __expf(e0), w1 = __expf(e1);
        lds_atom8(&acc[dl0][lane * 8], q0, w0);
        lds_atom8(&acc[dl1][lane * 8], q1, w1);
        if (lane == 0) {
            atomicAdd(&smv[dl0], w0);
            atomicAdd(&smv[dl1], w1);
        }
    }
    for (; i < m; i += 32) {
        int j = sidx[i];
        unsigned p = pb[j];
        int s = (int)(p & 0x00FFFFFFu);
        int dl = (int)(p >> 24) & 127;
        uint4 q = *(const uint4*)(h16 + (size_t)s * 64 + lane * 8);
        float e = als[s] + alds[dl];
        e = (e >= 0.0f) ? e : 0.2f * e;
        float w = __expf(e);
        lds_atom8(&acc[dl][lane * 8], q, w);
        if (lane == 0) atomicAdd(&smv[dl], w);
    }
    __syncthreads();

    // normalize + write out (coalesced 256B rows)
    for (int r = grp; r < 128; r += 32) {
        if (r < nbk) {
            float inv = 1.0f / (smv[r] + 1e-16f);
            float* row = &acc[r][lane * 8];
            float* op = hout + (size_t)(d0 + r) * 64 + lane * 8;
            op[0] = row[0] * inv;
            op[1] = row[1] * inv;
            op[2] = row[2] * inv;
            op[3] = row[3] * inv;
            op[4] = row[4] * inv;
            op[5] = row[5] * inv;
            op[6] = row[6] * inv;
            op[7] = row[7] * inv;
        }
    }
}

// --- fused pool + FC: one block per graph, binary-search batch bounds -------
__global__ __launch_bounds__(256) void pool_fc(const float* __restrict__ hout,
                                               const float* __restrict__ b2,
                                               const int* __restrict__ batch,
                                               const float* __restrict__ fcW,
                                               const float* __restrict__ fcb,
                                               float* __restrict__ out, int n) {
    int g = blockIdx.x;
    int t = threadIdx.x;
    __shared__ int sLo, sHi;
    __shared__ float red[4][64];
    if (t == 0) {
        int lo = 0, hi = n;
        while (lo < hi) { int m = (lo + hi) >> 1; if (batch[m] < g) lo = m + 1; else hi = m; }
        sLo = lo;
    } else if (t == 64) {
        int lo = 0, hi = n;
        while (lo < hi) { int m = (lo + hi) >> 1; if (batch[m] < g + 1) lo = m + 1; else hi = m; }
        sHi = lo;
    }
    __syncthreads();
    int lo = sLo, hi = sHi;
    int wv = t >> 6, lane = t & 63;
    float acc = 0.0f;
    for (int node = lo + wv; node < hi; node += 4)
        acc += hout[(size_t)node * 64 + lane];
    red[wv][lane] = acc;
    __syncthreads();
    if (wv == 0) {
        float c = (float)(hi - lo);
        float s = red[0][lane] + red[1][lane] + red[2][lane] + red[3][lane];
        s += c * b2[lane];
        float cd = (c > 1.0f) ? c : 1.0f;
        float p = s / cd;
        float s0 = p * fcW[lane * 2 + 0];
        float s1 = p * fcW[lane * 2 + 1];
#pragma unroll
        for (int o = 32; o; o >>= 1) {
            s0 += __shfl_xor(s0, o);
            s1 += __shfl_xor(s1, o);
        }
        if (lane == 0) {
            out[g * 2 + 0] = s0 + fcb[0];
            out[g * 2 + 1] = s1 + fcb[1];
        }
    }
}

extern "C" void kernel_launch(void* const* d_in, const int* in_sizes, int n_in,
                              void* d_out, int out_size, void* d_ws, size_t ws_size,
                              hipStream_t stream) {
    const float* x    = (const float*)d_in[0];
    const int*   ei   = (const int*)d_in[1];
    const int*   batch= (const int*)d_in[2];
    const float* W1   = (const float*)d_in[3];
    const float* as1  = (const float*)d_in[4];
    const float* ad1  = (const float*)d_in[5];
    const float* b1   = (const float*)d_in[6];
    const float* W2   = (const float*)d_in[7];
    const float* as2  = (const float*)d_in[8];
    const float* ad2  = (const float*)d_in[9];
    const float* b2   = (const float*)d_in[10];
    const float* fcW  = (const float*)d_in[11];
    const float* fcb  = (const float*)d_in[12];
    float* out = (float*)d_out;

    const int N = in_sizes[2];       // 100000
    const int E = in_sizes[1] / 2;   // 1600000
    const int G = out_size / 2;      // 256
    const int NB = (N + NPB - 1) / NPB;   // 391 parent buckets

    // ws layout (~46.4 MiB): no CSR arrays anymore
    float* ws     = (float*)d_ws;
    float* bufO   = ws;                           // N*64 fp32        25.6 MB
    unsigned int* pairs = (unsigned int*)(bufO + (size_t)N * 64); // 7.2 MB
    float* als    = (float*)(pairs + (size_t)NB * PSTRIDE);  // N      0.4 MB
    float* ald    = als + N;                      // N                 0.4 MB
    int*   bcur   = (int*)(ald + N);              // NB
    unsigned short* bufH16 = (unsigned short*)(bcur + NB);  // N*64   12.8 MB

    dim3 b256(256);
    int gInit = (NB + 255) / 256;
    int gPart = (E + EPB - 1) / EPB;
    int gGemm = (N + 63) / 64;
    int gAgg  = NB * 2;   // 128-dst half-buckets

    // ---- build: single-pass fixed-stride partition only (edges only) ----
    init_all<<<gInit, b256, 0, stream>>>(bcur, NB);
    partition<<<gPart, b256, 0, stream>>>(ei, E, NB, bcur, pairs);

    // ---- layer 1 ----
    node_gemm<72><<<gGemm, b256, 0, stream>>>(x, W1, as1, ad1, nullptr, 0.0f,
                                              bufH16, als, ald, N);
    gat_aggregate<<<gAgg, b256, 0, stream>>>(pairs, bcur, als, ald, bufH16, bufO, N);

    // ---- layer 2 (input = leaky(bufO + b1, 0.01)) ----
    node_gemm<64><<<gGemm, b256, 0, stream>>>(bufO, W2, as2, ad2, b1, 0.01f,
                                              bufH16, als, ald, N);
    gat_aggregate<<<gAgg, b256, 0, stream>>>(pairs, bcur, als, ald, bufH16, bufO, N);

    // ---- fused pool + fc ----
    pool_fc<<<G, b256, 0, stream>>>(bufO, b2, batch, fcW, fcb, out, N);
}